// Round 24
// baseline (65.248 us; speedup 1.0000x reference)
//
#include <hip/hip_runtime.h>
#include <math.h>

#define B 1024
#define E 256
#define H 4
#define DH 64
#define L 192
#define NF 16384
#define NO 49152
#define BPB 4   // batches per block

// ---------------------------------------------------------------------------
// Kernel 0 (prep): blocks 0..191 transpose Wq, Wv, Wo into WT; blocks 192..196
// compute per-batch start offsets by binary search.
// ---------------------------------------------------------------------------
__global__ __launch_bounds__(256) void prep_kernel(
    const int* __restrict__ fb, const int* __restrict__ ob,
    int* __restrict__ start_f, int* __restrict__ start_o,
    const float* __restrict__ ipw, const float* __restrict__ opw,
    float* __restrict__ WT)
{
  int blk = blockIdx.x;
  if (blk < 192) {
    int m = blk / 64;
    int r = blk % 64;
    int bx = (r & 7) * 32, by = (r >> 3) * 32;
    const float* src = (m == 0) ? ipw : (m == 1 ? ipw + 2 * E * E : opw);
    float* dst = WT + (size_t)m * E * E;
    __shared__ float tile[32][33];
    int tx = threadIdx.x & 31, ty = threadIdx.x >> 5;
#pragma unroll
    for (int i = 0; i < 32; i += 8)
      tile[ty + i][tx] = src[(size_t)(by + ty + i) * E + bx + tx];
    __syncthreads();
#pragma unroll
    for (int i = 0; i < 32; i += 8)
      dst[(size_t)(bx + ty + i) * E + by + tx] = tile[tx][ty + i];
  } else {
    int b = (blk - 192) * 256 + threadIdx.x;
    if (b > B) return;
    int lo = 0, hi = NF;
    while (lo < hi) { int m = (lo + hi) >> 1; if (fb[m] < b) lo = m + 1; else hi = m; }
    start_f[b] = lo;
    lo = 0; hi = NO;
    while (lo < hi) { int m = (lo + hi) >> 1; if (ob[m] < b) lo = m + 1; else hi = m; }
    start_o[b] = lo;
  }
}

// ---------------------------------------------------------------------------
// Fused kernel: 4 batches/block, 1024 threads (16 waves = 4/SIMD), grid 256.
// Same weight traffic per block as the 51us version, 2x the waves.
//  q/ctx/out : wave (bw = w>>2, sub = w&3): 64-iter float4 loop, 4-way merge
//  Y         : wave (bw, h): direct full-dot into YZ_s
//  stream    : wave (bb = w>>2, hp = (w>>1)&1, rs = w&1): 2 heads, rows
//              s ≡ rs*4+g (mod 8); 2-way rowset merge. ~112 VGPR.
// LDS ~73 KB. launch_bounds(1024,4): cap 128 VGPR (>= natural ~120).
// ---------------------------------------------------------------------------
__global__ __launch_bounds__(1024, 4) void fused_kernel(
    const float* __restrict__ scene,
    const float* __restrict__ face, const float* __restrict__ obj,
    const float* __restrict__ ipw, const float* __restrict__ ipb,
    const float* __restrict__ WqT, const float* __restrict__ WvT,
    const float* __restrict__ WoT, const float* __restrict__ opb,
    const float* __restrict__ gamma, const float* __restrict__ beta,
    const int* __restrict__ start_f, const int* __restrict__ start_o,
    float* __restrict__ fusedO, float* __restrict__ attnw)
{
  int b0 = blockIdx.x * BPB;
  int t = threadIdx.x, wave = t >> 6, lane = t & 63;
  int bw = wave >> 2, sub = wave & 3;

  __shared__ float sc_s[BPB][E];       // 4 KB
  __shared__ float q_s[BPB][E];        // 4 KB (reused as x)
  __shared__ float YZ_s[BPB][H][E];    // 16 KB (Y, then Z)
  __shared__ float ctx_s[BPB][E];      // 4 KB
  __shared__ float s_s[BPB][H][L];     // 12 KB raw scores
  __shared__ float un_s[8192];         // 32 KB: q/ctx/out partials; stream Zp
  __shared__ float mw_s[BPB][2][2][2], su_s[BPB][2][2][2], sb_s[BPB][H];
  __shared__ int   info_s[BPB][4];

  if (t < BPB * E) ((float*)sc_s)[t] = scene[(size_t)b0 * E + t];
  if (t < BPB) {
    int b = b0 + t;
    int sf0 = start_f[b], cf = start_f[b + 1] - sf0;
    int so0 = start_o[b], co = start_o[b + 1] - so0;
    info_s[t][0] = sf0; info_s[t][1] = so0;
    info_s[t][2] = min(cf, L); info_s[t][3] = min(cf + co, L);
  }
  __syncthreads();

  // ---- q partials: wave (bw, jq=sub); j in [64*sub, 64*sub+64) ----
  {
    const float4* W4 = (const float4*)WqT + lane;
    const float* sc = sc_s[bw];
    float4 a = {0.f, 0.f, 0.f, 0.f};
    int j0 = sub * 64;
#pragma unroll 8
    for (int jj = 0; jj < 64; ++jj) {
      int j = j0 + jj;
      float4 w = W4[(size_t)j * 64];
      float s = sc[j];
      a.x += s * w.x; a.y += s * w.y; a.z += s * w.z; a.w += s * w.w;
    }
    // part(sub, bw, e) = un_s[(sub*BPB+bw)<<8 + e]
    *(float4*)&un_s[((sub * BPB + bw) << 8) + 4 * lane] = a;
  }
  __syncthreads();
  if (t < BPB * E) {
    int bi = t >> 8, e = t & 255;
    q_s[bi][e] = un_s[((0 * BPB + bi) << 8) + e] + un_s[((1 * BPB + bi) << 8) + e] +
                 un_s[((2 * BPB + bi) << 8) + e] + un_s[((3 * BPB + bi) << 8) + e] + ipb[e];
  }
  __syncthreads();

  // ---- sb (waves 0..3, batch = wave) + Y (all 16 waves: (bw, h=sub)) ----
  if (wave < BPB) {
#pragma unroll
    for (int h = 0; h < H; ++h) {
      float v = q_s[wave][h * DH + lane] * ipb[E + h * DH + lane];
#pragma unroll
      for (int o = 32; o; o >>= 1) v += __shfl_xor(v, o);
      if (lane == 0) sb_s[wave][h] = v;
    }
  }
  {
    const float* Wk = ipw + (size_t)E * E;
    float4 a = {0.f, 0.f, 0.f, 0.f};
#pragma unroll 8
    for (int d = 0; d < DH; ++d) {
      float qv = q_s[bw][sub * DH + d];
      float4 w = *((const float4*)(Wk + (size_t)(sub * DH + d) * E) + lane);
      a.x += qv * w.x; a.y += qv * w.y; a.z += qv * w.z; a.w += qv * w.w;
    }
    *(float4*)&YZ_s[bw][sub][4 * lane] = a;
  }
  __syncthreads();

  // ---- X-stream: wave = (bb = w>>2, hp = (w>>1)&1, rs = w&1) ----
  {
    int bb = wave >> 2, hp = (wave >> 1) & 1, rs = wave & 1, h0 = hp * 2;
    int g = lane >> 4, sl = lane & 15;
    int sf0 = info_s[bb][0], so0 = info_s[bb][1];
    int n_f = info_s[bb][2], n = info_s[bb][3];

    float4 y[2][4];
#pragma unroll
    for (int hh = 0; hh < 2; ++hh)
#pragma unroll
      for (int k = 0; k < 4; ++k)
        y[hh][k] = *(const float4*)&YZ_s[bb][h0 + hh][4 * (sl + 16 * k)];
    float sbv[2] = {sb_s[bb][h0], sb_s[bb][h0 + 1]};

    float m[2] = {-3.0e38f, -3.0e38f};
    float u[2] = {0.f, 0.f};
    float4 acc[2][4] = {};

    int s0 = rs * 4 + g;               // rows ≡ rs*4+g (mod 8)
    float4 x[4] = {};
    if (s0 < n) {
      const float* xr = (s0 < n_f) ? face + (size_t)(sf0 + s0) * E
                                   : obj  + (size_t)(so0 + s0 - n_f) * E;
#pragma unroll
      for (int k = 0; k < 4; ++k) x[k] = ((const float4*)xr)[sl + 16 * k];
    }

    for (int s = s0; s < n; s += 8) {
      float4 xn[4] = {};
      int sn = s + 8;
      if (sn < n) {
        const float* xr = (sn < n_f) ? face + (size_t)(sf0 + sn) * E
                                     : obj  + (size_t)(so0 + sn - n_f) * E;
#pragma unroll
        for (int k = 0; k < 4; ++k) xn[k] = ((const float4*)xr)[sl + 16 * k];
      }

      float p[2];
#pragma unroll
      for (int hh = 0; hh < 2; ++hh) {
        float a = 0.f;
#pragma unroll
        for (int k = 0; k < 4; ++k)
          a += x[k].x * y[hh][k].x + x[k].y * y[hh][k].y +
               x[k].z * y[hh][k].z + x[k].w * y[hh][k].w;
        p[hh] = a;
      }
#pragma unroll
      for (int off = 8; off; off >>= 1) {
        p[0] += __shfl_xor(p[0], off);
        p[1] += __shfl_xor(p[1], off);
      }
      p[0] = (p[0] + sbv[0]) * 0.125f;
      p[1] = (p[1] + sbv[1]) * 0.125f;
      if (sl == 0) {
        s_s[bb][h0][s] = p[0];
        s_s[bb][h0 + 1][s] = p[1];
      }
#pragma unroll
      for (int hh = 0; hh < 2; ++hh) {
        if (p[hh] > m[hh]) {
          float f = __expf(m[hh] - p[hh]);
#pragma unroll
          for (int k = 0; k < 4; ++k) {
            acc[hh][k].x = acc[hh][k].x * f + x[k].x;
            acc[hh][k].y = acc[hh][k].y * f + x[k].y;
            acc[hh][k].z = acc[hh][k].z * f + x[k].z;
            acc[hh][k].w = acc[hh][k].w * f + x[k].w;
          }
          u[hh] = u[hh] * f + 1.f;
          m[hh] = p[hh];
        } else {
          float e = __expf(p[hh] - m[hh]);
#pragma unroll
          for (int k = 0; k < 4; ++k) {
            acc[hh][k].x += e * x[k].x;
            acc[hh][k].y += e * x[k].y;
            acc[hh][k].z += e * x[k].z;
            acc[hh][k].w += e * x[k].w;
          }
          u[hh] += e;
        }
      }
#pragma unroll
      for (int k = 0; k < 4; ++k) x[k] = xn[k];
    }

    // merge 4 groups within the wave (xor 16, 32)
#pragma unroll
    for (int off = 16; off <= 32; off <<= 1) {
#pragma unroll
      for (int hh = 0; hh < 2; ++hh) {
        float mo = __shfl_xor(m[hh], off);
        float uo = __shfl_xor(u[hh], off);
        float M = fmaxf(m[hh], mo);
        float fs = __expf(m[hh] - M), fo = __expf(mo - M);
        u[hh] = fs * u[hh] + fo * uo;
        m[hh] = M;
#pragma unroll
        for (int k = 0; k < 4; ++k) {
          float ax = __shfl_xor(acc[hh][k].x, off);
          float ay = __shfl_xor(acc[hh][k].y, off);
          float az = __shfl_xor(acc[hh][k].z, off);
          float aw = __shfl_xor(acc[hh][k].w, off);
          acc[hh][k].x = fs * acc[hh][k].x + fo * ax;
          acc[hh][k].y = fs * acc[hh][k].y + fo * ay;
          acc[hh][k].z = fs * acc[hh][k].z + fo * az;
          acc[hh][k].w = fs * acc[hh][k].w + fo * aw;
        }
      }
    }
    // Zp(bb, hp, rs, hh, e) = un_s[(((bb*2+hp)*2+rs)*2+hh)<<8 + e]
    if (g == 0) {
#pragma unroll
      for (int hh = 0; hh < 2; ++hh)
#pragma unroll
        for (int k = 0; k < 4; ++k)
          *(float4*)&un_s[((((bb * 2 + hp) * 2 + rs) * 2 + hh) << 8) + 4 * (sl + 16 * k)] = acc[hh][k];
    }
    if (lane == 0) {
      mw_s[bb][hp][rs][0] = m[0]; mw_s[bb][hp][rs][1] = m[1];
      su_s[bb][hp][rs][0] = u[0]; su_s[bb][hp][rs][1] = u[1];
    }
  }
  __syncthreads();

  // ---- merge rowsets + normalize Z into YZ_s ----
  for (int i = t; i < BPB * H * E; i += 1024) {
    int bi = i >> 10, rem = i & 1023, h = rem >> 8, e = rem & 255;
    float z = 0.f;
    if (info_s[bi][3] > 0) {
      int hp = h >> 1, hh = h & 1;
      float ma = mw_s[bi][hp][0][hh], mb = mw_s[bi][hp][1][hh];
      float M = fmaxf(ma, mb);
      float fa = __expf(ma - M), fb = __expf(mb - M);
      float inv = 1.0f / (fa * su_s[bi][hp][0][hh] + fb * su_s[bi][hp][1][hh]);
      z = (fa * un_s[((((bi * 2 + hp) * 2 + 0) * 2 + hh) << 8) + e] +
           fb * un_s[((((bi * 2 + hp) * 2 + 1) * 2 + hh) << 8) + e]) * inv;
    }
    ((float*)YZ_s)[i] = z;
  }
  // ---- attnw (BPB*L = 768 <= 1024) ----
  if (t < BPB * L) {
    int bi = t / L, s = t - bi * L;
    int n = info_s[bi][3];
    float v;
    if (n == 0) v = 1.0f / L;
    else if (s < n) {
      v = 0.f;
#pragma unroll
      for (int h = 0; h < H; ++h) {
        int hp = h >> 1, hh = h & 1;
        float ma = mw_s[bi][hp][0][hh], mb = mw_s[bi][hp][1][hh];
        float M = fmaxf(ma, mb);
        float fa = __expf(ma - M), fb = __expf(mb - M);
        float inv = 1.0f / (fa * su_s[bi][hp][0][hh] + fb * su_s[bi][hp][1][hh]);
        v += __expf(s_s[bi][h][s] - M) * inv;
      }
      v *= 0.25f;
    } else v = 0.f;
    attnw[(size_t)(b0 + bi) * L + s] = v;
  }
  __syncthreads();

  // ---- ctx partials: wave (bw, jq=sub); head(outputs 4l..) = l>>4 ----
  {
    const float4* W4 = (const float4*)WvT + lane;
    const float* zr = YZ_s[bw][lane >> 4];
    float4 a = {0.f, 0.f, 0.f, 0.f};
    int j0 = sub * 64;
#pragma unroll 8
    for (int jj = 0; jj < 64; ++jj) {
      int j = j0 + jj;
      float4 w = W4[(size_t)j * 64];
      float zv = zr[j];
      a.x += zv * w.x; a.y += zv * w.y; a.z += zv * w.z; a.w += zv * w.w;
    }
    *(float4*)&un_s[((sub * BPB + bw) << 8) + 4 * lane] = a;
  }
  __syncthreads();
  if (t < BPB * E) {
    int bi = t >> 8, e = t & 255;
    ctx_s[bi][e] = un_s[((0 * BPB + bi) << 8) + e] + un_s[((1 * BPB + bi) << 8) + e] +
                   un_s[((2 * BPB + bi) << 8) + e] + un_s[((3 * BPB + bi) << 8) + e] +
                   ipb[2 * E + e];
  }
  __syncthreads();

  // ---- out-proj partials ----
  {
    const float4* W4 = (const float4*)WoT + lane;
    const float* cr = ctx_s[bw];
    float4 a = {0.f, 0.f, 0.f, 0.f};
    int j0 = sub * 64;
#pragma unroll 8
    for (int jj = 0; jj < 64; ++jj) {
      int j = j0 + jj;
      float4 w = W4[(size_t)j * 64];
      float cv = cr[j];
      a.x += cv * w.x; a.y += cv * w.y; a.z += cv * w.z; a.w += cv * w.w;
    }
    *(float4*)&un_s[((sub * BPB + bw) << 8) + 4 * lane] = a;
  }
  __syncthreads();
  if (t < BPB * E) {
    int bi = t >> 8, e = t & 255;
    q_s[bi][e] = un_s[((0 * BPB + bi) << 8) + e] + un_s[((1 * BPB + bi) << 8) + e] +
                 un_s[((2 * BPB + bi) << 8) + e] + un_s[((3 * BPB + bi) << 8) + e] +
                 opb[e] + sc_s[bi][e];
  }
  __syncthreads();

  // ---- LayerNorm: waves 0..3, one batch each ----
  if (wave < BPB) {
    float v0 = q_s[wave][lane], v1 = q_s[wave][lane + 64],
          v2 = q_s[wave][lane + 128], v3 = q_s[wave][lane + 192];
    float s1 = v0 + v1 + v2 + v3;
#pragma unroll
    for (int o = 32; o; o >>= 1) s1 += __shfl_xor(s1, o);
    float mu = s1 * (1.0f / E);
    float d0 = v0 - mu, d1 = v1 - mu, d2 = v2 - mu, d3 = v3 - mu;
    float s2 = d0*d0 + d1*d1 + d2*d2 + d3*d3;
#pragma unroll
    for (int o = 32; o; o >>= 1) s2 += __shfl_xor(s2, o);
    float inv = 1.0f / sqrtf(s2 * (1.0f / E) + 1e-5f);
    size_t base = (size_t)(b0 + wave) * E;
    fusedO[base + lane      ] = d0 * inv * gamma[lane      ] + beta[lane      ];
    fusedO[base + lane +  64] = d1 * inv * gamma[lane +  64] + beta[lane +  64];
    fusedO[base + lane + 128] = d2 * inv * gamma[lane + 128] + beta[lane + 128];
    fusedO[base + lane + 192] = d3 * inv * gamma[lane + 192] + beta[lane + 192];
  }
}

// ---------------------------------------------------------------------------
extern "C" void kernel_launch(void* const* d_in, const int* in_sizes, int n_in,
                              void* d_out, int out_size, void* d_ws, size_t ws_size,
                              hipStream_t stream) {
  const float* scene = (const float*)d_in[0];
  const float* face  = (const float*)d_in[1];
  const float* obj   = (const float*)d_in[2];
  const int*   fb    = (const int*)d_in[3];
  const int*   ob    = (const int*)d_in[4];
  const float* ipw   = (const float*)d_in[5];
  const float* ipb   = (const float*)d_in[6];
  const float* opw   = (const float*)d_in[7];
  const float* opb   = (const float*)d_in[8];
  const float* gam   = (const float*)d_in[9];
  const float* bet   = (const float*)d_in[10];

  float* fused = (float*)d_out;
  float* attnw = fused + (size_t)B * E;

  // ws: starts (16KB) | WT (768KB)
  int* start_f = (int*)d_ws;
  int* start_o = start_f + (B + 1);
  float* WT   = (float*)((char*)d_ws + (16 << 10));
  float* WqT = WT;
  float* WvT = WT + (size_t)E * E;
  float* WoT = WT + (size_t)2 * E * E;

  prep_kernel<<<197, 256, 0, stream>>>(fb, ob, start_f, start_o, ipw, opw, WT);
  fused_kernel<<<B / BPB, 1024, 0, stream>>>(scene, face, obj, ipw, ipb,
                                             WqT, WvT, WoT, opb, gam, bet,
                                             start_f, start_o, fused, attnw);
}

// Round 25
// 50.438 us; speedup vs baseline: 1.2936x; 1.2936x over previous
//
#include <hip/hip_runtime.h>
#include <math.h>

#define B 1024
#define E 256
#define H 4
#define DH 64
#define L 192
#define NF 16384
#define NO 49152
#define BPB 4   // batches per block

// ---------------------------------------------------------------------------
// Kernel 0 (prep): blocks 0..191 transpose Wq, Wv, Wo into WT; blocks 192..196
// compute per-batch start offsets by binary search.
// ---------------------------------------------------------------------------
__global__ __launch_bounds__(256) void prep_kernel(
    const int* __restrict__ fb, const int* __restrict__ ob,
    int* __restrict__ start_f, int* __restrict__ start_o,
    const float* __restrict__ ipw, const float* __restrict__ opw,
    float* __restrict__ WT)
{
  int blk = blockIdx.x;
  if (blk < 192) {
    int m = blk / 64;
    int r = blk % 64;
    int bx = (r & 7) * 32, by = (r >> 3) * 32;
    const float* src = (m == 0) ? ipw : (m == 1 ? ipw + 2 * E * E : opw);
    float* dst = WT + (size_t)m * E * E;
    __shared__ float tile[32][33];
    int tx = threadIdx.x & 31, ty = threadIdx.x >> 5;
#pragma unroll
    for (int i = 0; i < 32; i += 8)
      tile[ty + i][tx] = src[(size_t)(by + ty + i) * E + bx + tx];
    __syncthreads();
#pragma unroll
    for (int i = 0; i < 32; i += 8)
      dst[(size_t)(bx + ty + i) * E + by + tx] = tile[tx][ty + i];
  } else {
    int b = (blk - 192) * 256 + threadIdx.x;
    if (b > B) return;
    int lo = 0, hi = NF;
    while (lo < hi) { int m = (lo + hi) >> 1; if (fb[m] < b) lo = m + 1; else hi = m; }
    start_f[b] = lo;
    lo = 0; hi = NO;
    while (lo < hi) { int m = (lo + hi) >> 1; if (ob[m] < b) lo = m + 1; else hi = m; }
    start_o[b] = lo;
  }
}

// ---------------------------------------------------------------------------
// Fused kernel: 4 batches/block, 512 threads (8 waves), grid 256.
// Identical to the 51.0us version EXCEPT the X-stream processes row PAIRS
// (s, s+4) per iteration with prefetch of (s+8, s+12): 4 outstanding loads,
// doubled dot ILP. launch_bounds(512,2): no VGPR cap below 256 (no spill).
// ---------------------------------------------------------------------------
__global__ __launch_bounds__(512, 2) void fused_kernel(
    const float* __restrict__ scene,
    const float* __restrict__ face, const float* __restrict__ obj,
    const float* __restrict__ ipw, const float* __restrict__ ipb,
    const float* __restrict__ WqT, const float* __restrict__ WvT,
    const float* __restrict__ WoT, const float* __restrict__ opb,
    const float* __restrict__ gamma, const float* __restrict__ beta,
    const int* __restrict__ start_f, const int* __restrict__ start_o,
    float* __restrict__ fusedO, float* __restrict__ attnw)
{
  int b0 = blockIdx.x * BPB;
  int t = threadIdx.x, wave = t >> 6, lane = t & 63;

  __shared__ float sc_s[BPB][E];       // 4 KB
  __shared__ float q_s[BPB][E];        // 4 KB (reused as x)
  __shared__ float YZ_s[BPB][H][E];    // 16 KB (Y, then Z)
  __shared__ float ctx_s[BPB][E];      // 4 KB
  __shared__ float s_s[BPB][H][L];     // 12 KB raw scores
  __shared__ float un_s[8192];         // 32 KB time-multiplexed partials
  __shared__ float mw_s[BPB][2][2], su_s[BPB][2][2], sb_s[BPB][H];
  __shared__ int   info_s[BPB][4];

  for (int i = t; i < BPB * E; i += 512)
    ((float*)sc_s)[i] = scene[(size_t)b0 * E + i];
  if (t < BPB) {
    int b = b0 + t;
    int sf0 = start_f[b], cf = start_f[b + 1] - sf0;
    int so0 = start_o[b], co = start_o[b + 1] - so0;
    info_s[t][0] = sf0; info_s[t][1] = so0;
    info_s[t][2] = min(cf, L); info_s[t][3] = min(cf + co, L);
  }
  __syncthreads();

  // ---- q partials: wave covers j in [32w,32w+32); lane owns 4 outs ----
  {
    const float4* W4 = (const float4*)WqT + lane;
    float4 a0 = {0,0,0,0}, a1 = {0,0,0,0}, a2 = {0,0,0,0}, a3 = {0,0,0,0};
    int j0 = wave * 32;
#pragma unroll
    for (int jj = 0; jj < 32; ++jj) {
      int j = j0 + jj;
      float4 w = W4[(size_t)j * 64];
      float s0 = sc_s[0][j], s1 = sc_s[1][j], s2 = sc_s[2][j], s3 = sc_s[3][j];
      a0.x += s0*w.x; a0.y += s0*w.y; a0.z += s0*w.z; a0.w += s0*w.w;
      a1.x += s1*w.x; a1.y += s1*w.y; a1.z += s1*w.z; a1.w += s1*w.w;
      a2.x += s2*w.x; a2.y += s2*w.y; a2.z += s2*w.z; a2.w += s2*w.w;
      a3.x += s3*w.x; a3.y += s3*w.y; a3.z += s3*w.z; a3.w += s3*w.w;
    }
    *(float4*)&un_s[((wave * BPB + 0) << 8) + 4 * lane] = a0;
    *(float4*)&un_s[((wave * BPB + 1) << 8) + 4 * lane] = a1;
    *(float4*)&un_s[((wave * BPB + 2) << 8) + 4 * lane] = a2;
    *(float4*)&un_s[((wave * BPB + 3) << 8) + 4 * lane] = a3;
  }
  __syncthreads();
  for (int i = t; i < BPB * E; i += 512) {
    int bi = i >> 8, e = i & 255;
    float v = ipb[e];
#pragma unroll
    for (int w = 0; w < 8; ++w) v += un_s[((w * BPB + bi) << 8) + e];
    q_s[bi][e] = v;
  }
  __syncthreads();

  // ---- sb (waves 0..3, batch = wave) ----
  if (wave < BPB) {
#pragma unroll
    for (int h = 0; h < H; ++h) {
      float v = q_s[wave][h * DH + lane] * ipb[E + h * DH + lane];
#pragma unroll
      for (int o = 32; o; o >>= 1) v += __shfl_xor(v, o);
      if (lane == 0) sb_s[wave][h] = v;
    }
  }

  // ---- Y partials: wave -> (h = wave>>1, half wi = wave&1) ----
  {
    const float* Wk = ipw + (size_t)E * E;
    int h = wave >> 1, d0 = (wave & 1) * 32, wi = wave & 1;
    float4 a0 = {0,0,0,0}, a1 = {0,0,0,0}, a2 = {0,0,0,0}, a3 = {0,0,0,0};
#pragma unroll
    for (int dd = 0; dd < 32; ++dd) {
      int d = d0 + dd;
      float4 w = *((const float4*)(Wk + (size_t)(h * DH + d) * E) + lane);
      float q0 = q_s[0][h * DH + d], q1 = q_s[1][h * DH + d];
      float q2 = q_s[2][h * DH + d], q3 = q_s[3][h * DH + d];
      a0.x += q0*w.x; a0.y += q0*w.y; a0.z += q0*w.z; a0.w += q0*w.w;
      a1.x += q1*w.x; a1.y += q1*w.y; a1.z += q1*w.z; a1.w += q1*w.w;
      a2.x += q2*w.x; a2.y += q2*w.y; a2.z += q2*w.z; a2.w += q2*w.w;
      a3.x += q3*w.x; a3.y += q3*w.y; a3.z += q3*w.z; a3.w += q3*w.w;
    }
    // Yp(wi, bi, h, e) = un_s[wi*4096 + ((bi*H)+h)*256 + e]
    *(float4*)&un_s[wi * 4096 + ((0 * H + h) << 8) + 4 * lane] = a0;
    *(float4*)&un_s[wi * 4096 + ((1 * H + h) << 8) + 4 * lane] = a1;
    *(float4*)&un_s[wi * 4096 + ((2 * H + h) << 8) + 4 * lane] = a2;
    *(float4*)&un_s[wi * 4096 + ((3 * H + h) << 8) + 4 * lane] = a3;
  }
  __syncthreads();
  for (int i = t; i < BPB * H * E; i += 512)
    ((float*)YZ_s)[i] = un_s[i] + un_s[4096 + i];
  __syncthreads();

  // ---- X-stream: wave = (bb = wave>>1, hp = wave&1); 2 heads/wave ----
  //      row pairs (s, s+4) per iteration, prefetch (s+8, s+12)
  {
    int bb = wave >> 1, hp = wave & 1, h0 = hp * 2;
    int g = lane >> 4, sl = lane & 15;
    int sf0 = info_s[bb][0], so0 = info_s[bb][1];
    int n_f = info_s[bb][2], n = info_s[bb][3];

    float4 y[2][4];
#pragma unroll
    for (int hh = 0; hh < 2; ++hh)
#pragma unroll
      for (int k = 0; k < 4; ++k)
        y[hh][k] = *(const float4*)&YZ_s[bb][h0 + hh][4 * (sl + 16 * k)];
    float sbv[2] = {sb_s[bb][h0], sb_s[bb][h0 + 1]};

    float m[2] = {-3.0e38f, -3.0e38f};
    float u[2] = {0.f, 0.f};
    float4 acc[2][4] = {};

    float4 xA[4] = {}, xB[4] = {};
    if (g < n) {
      const float* xr = (g < n_f) ? face + (size_t)(sf0 + g) * E
                                  : obj  + (size_t)(so0 + g - n_f) * E;
#pragma unroll
      for (int k = 0; k < 4; ++k) xA[k] = ((const float4*)xr)[sl + 16 * k];
    }
    if (g + 4 < n) {
      int sB0 = g + 4;
      const float* xr = (sB0 < n_f) ? face + (size_t)(sf0 + sB0) * E
                                    : obj  + (size_t)(so0 + sB0 - n_f) * E;
#pragma unroll
      for (int k = 0; k < 4; ++k) xB[k] = ((const float4*)xr)[sl + 16 * k];
    }

    for (int s = g; s < n; s += 8) {
      int sB = s + 4;
      float4 xnA[4] = {}, xnB[4] = {};
      if (s + 8 < n) {
        int sn = s + 8;
        const float* xr = (sn < n_f) ? face + (size_t)(sf0 + sn) * E
                                     : obj  + (size_t)(so0 + sn - n_f) * E;
#pragma unroll
        for (int k = 0; k < 4; ++k) xnA[k] = ((const float4*)xr)[sl + 16 * k];
      }
      if (s + 12 < n) {
        int sn = s + 12;
        const float* xr = (sn < n_f) ? face + (size_t)(sf0 + sn) * E
                                     : obj  + (size_t)(so0 + sn - n_f) * E;
#pragma unroll
        for (int k = 0; k < 4; ++k) xnB[k] = ((const float4*)xr)[sl + 16 * k];
      }

      float pA[2], pB[2];
#pragma unroll
      for (int hh = 0; hh < 2; ++hh) {
        float a = 0.f, b = 0.f;
#pragma unroll
        for (int k = 0; k < 4; ++k) {
          a += xA[k].x * y[hh][k].x + xA[k].y * y[hh][k].y +
               xA[k].z * y[hh][k].z + xA[k].w * y[hh][k].w;
          b += xB[k].x * y[hh][k].x + xB[k].y * y[hh][k].y +
               xB[k].z * y[hh][k].z + xB[k].w * y[hh][k].w;
        }
        pA[hh] = a; pB[hh] = b;
      }
#pragma unroll
      for (int off = 8; off; off >>= 1) {
        pA[0] += __shfl_xor(pA[0], off);
        pA[1] += __shfl_xor(pA[1], off);
        pB[0] += __shfl_xor(pB[0], off);
        pB[1] += __shfl_xor(pB[1], off);
      }
      pA[0] = (pA[0] + sbv[0]) * 0.125f;
      pA[1] = (pA[1] + sbv[1]) * 0.125f;
      pB[0] = (pB[0] + sbv[0]) * 0.125f;
      pB[1] = (pB[1] + sbv[1]) * 0.125f;
      if (sl == 0) {
        s_s[bb][h0][s] = pA[0];
        s_s[bb][h0 + 1][s] = pA[1];
        if (sB < n) {
          s_s[bb][h0][sB] = pB[0];
          s_s[bb][h0 + 1][sB] = pB[1];
        }
      }
      // online update row A
#pragma unroll
      for (int hh = 0; hh < 2; ++hh) {
        if (pA[hh] > m[hh]) {
          float f = __expf(m[hh] - pA[hh]);
#pragma unroll
          for (int k = 0; k < 4; ++k) {
            acc[hh][k].x = acc[hh][k].x * f + xA[k].x;
            acc[hh][k].y = acc[hh][k].y * f + xA[k].y;
            acc[hh][k].z = acc[hh][k].z * f + xA[k].z;
            acc[hh][k].w = acc[hh][k].w * f + xA[k].w;
          }
          u[hh] = u[hh] * f + 1.f;
          m[hh] = pA[hh];
        } else {
          float e = __expf(pA[hh] - m[hh]);
#pragma unroll
          for (int k = 0; k < 4; ++k) {
            acc[hh][k].x += e * xA[k].x;
            acc[hh][k].y += e * xA[k].y;
            acc[hh][k].z += e * xA[k].z;
            acc[hh][k].w += e * xA[k].w;
          }
          u[hh] += e;
        }
      }
      // online update row B
      if (sB < n) {
#pragma unroll
        for (int hh = 0; hh < 2; ++hh) {
          if (pB[hh] > m[hh]) {
            float f = __expf(m[hh] - pB[hh]);
#pragma unroll
            for (int k = 0; k < 4; ++k) {
              acc[hh][k].x = acc[hh][k].x * f + xB[k].x;
              acc[hh][k].y = acc[hh][k].y * f + xB[k].y;
              acc[hh][k].z = acc[hh][k].z * f + xB[k].z;
              acc[hh][k].w = acc[hh][k].w * f + xB[k].w;
            }
            u[hh] = u[hh] * f + 1.f;
            m[hh] = pB[hh];
          } else {
            float e = __expf(pB[hh] - m[hh]);
#pragma unroll
            for (int k = 0; k < 4; ++k) {
              acc[hh][k].x += e * xB[k].x;
              acc[hh][k].y += e * xB[k].y;
              acc[hh][k].z += e * xB[k].z;
              acc[hh][k].w += e * xB[k].w;
            }
            u[hh] += e;
          }
        }
      }
#pragma unroll
      for (int k = 0; k < 4; ++k) { xA[k] = xnA[k]; xB[k] = xnB[k]; }
    }

    // merge 4 groups within the wave (xor 16, 32)
#pragma unroll
    for (int off = 16; off <= 32; off <<= 1) {
#pragma unroll
      for (int hh = 0; hh < 2; ++hh) {
        float mo = __shfl_xor(m[hh], off);
        float uo = __shfl_xor(u[hh], off);
        float M = fmaxf(m[hh], mo);
        float fs = __expf(m[hh] - M), fo = __expf(mo - M);
        u[hh] = fs * u[hh] + fo * uo;
        m[hh] = M;
#pragma unroll
        for (int k = 0; k < 4; ++k) {
          float ax = __shfl_xor(acc[hh][k].x, off);
          float ay = __shfl_xor(acc[hh][k].y, off);
          float az = __shfl_xor(acc[hh][k].z, off);
          float aw = __shfl_xor(acc[hh][k].w, off);
          acc[hh][k].x = fs * acc[hh][k].x + fo * ax;
          acc[hh][k].y = fs * acc[hh][k].y + fo * ay;
          acc[hh][k].z = fs * acc[hh][k].z + fo * az;
          acc[hh][k].w = fs * acc[hh][k].w + fo * aw;
        }
      }
    }
    // Zp(bb, hp, hh, e) = un_s[((bb*2+hp)*2+hh)*256 + e]
    if (g == 0) {
#pragma unroll
      for (int hh = 0; hh < 2; ++hh)
#pragma unroll
        for (int k = 0; k < 4; ++k)
          *(float4*)&un_s[(((bb * 2 + hp) * 2 + hh) << 8) + 4 * (sl + 16 * k)] = acc[hh][k];
    }
    if (lane == 0) {
      mw_s[bb][hp][0] = m[0]; mw_s[bb][hp][1] = m[1];
      su_s[bb][hp][0] = u[0]; su_s[bb][hp][1] = u[1];
    }
  }
  __syncthreads();

  // ---- normalize Z into YZ_s (each head owned by one wave: no merge) ----
  for (int i = t; i < BPB * H * E; i += 512) {
    int bi = i >> 10, rem = i & 1023, h = rem >> 8, e = rem & 255;
    float z = 0.f;
    if (info_s[bi][3] > 0) {
      int hp = h >> 1, hh = h & 1;
      float inv = 1.0f / su_s[bi][hp][hh];
      z = un_s[(((bi * 2 + hp) * 2 + hh) << 8) + e] * inv;
    }
    ((float*)YZ_s)[i] = z;
  }
  // ---- attnw (BPB*L = 768 > 512: loop) ----
  for (int i = t; i < BPB * L; i += 512) {
    int bi = i / L, s = i - bi * L;
    int n = info_s[bi][3];
    float v;
    if (n == 0) v = 1.0f / L;
    else if (s < n) {
      v = 0.f;
#pragma unroll
      for (int h = 0; h < H; ++h) {
        int hp = h >> 1, hh = h & 1;
        v += __expf(s_s[bi][h][s] - mw_s[bi][hp][hh]) / su_s[bi][hp][hh];
      }
      v *= 0.25f;
    } else v = 0.f;
    attnw[(size_t)(b0 + bi) * L + s] = v;
  }
  __syncthreads();

  // ---- ctx partials: wave covers j in [32w,32w+32); head(4l..) = l>>4 ----
  {
    const float4* W4 = (const float4*)WvT + lane;
    int j0 = wave * 32, hoff = (lane >> 4) * E;
    float4 a0 = {0,0,0,0}, a1 = {0,0,0,0}, a2 = {0,0,0,0}, a3 = {0,0,0,0};
#pragma unroll
    for (int jj = 0; jj < 32; ++jj) {
      int j = j0 + jj;
      float4 w = W4[(size_t)j * 64];
      float z0 = ((float*)YZ_s[0])[hoff + j];
      float z1 = ((float*)YZ_s[1])[hoff + j];
      float z2 = ((float*)YZ_s[2])[hoff + j];
      float z3 = ((float*)YZ_s[3])[hoff + j];
      a0.x += z0*w.x; a0.y += z0*w.y; a0.z += z0*w.z; a0.w += z0*w.w;
      a1.x += z1*w.x; a1.y += z1*w.y; a1.z += z1*w.z; a1.w += z1*w.w;
      a2.x += z2*w.x; a2.y += z2*w.y; a2.z += z2*w.z; a2.w += z2*w.w;
      a3.x += z3*w.x; a3.y += z3*w.y; a3.z += z3*w.z; a3.w += z3*w.w;
    }
    *(float4*)&un_s[((wave * BPB + 0) << 8) + 4 * lane] = a0;
    *(float4*)&un_s[((wave * BPB + 1) << 8) + 4 * lane] = a1;
    *(float4*)&un_s[((wave * BPB + 2) << 8) + 4 * lane] = a2;
    *(float4*)&un_s[((wave * BPB + 3) << 8) + 4 * lane] = a3;
  }
  __syncthreads();
  for (int i = t; i < BPB * E; i += 512) {
    int bi = i >> 8, e = i & 255;
    float v = ipb[2 * E + e];
#pragma unroll
    for (int w = 0; w < 8; ++w) v += un_s[((w * BPB + bi) << 8) + e];
    ctx_s[bi][e] = v;
  }
  __syncthreads();

  // ---- out-proj partials ----
  {
    const float4* W4 = (const float4*)WoT + lane;
    int j0 = wave * 32;
    float4 a0 = {0,0,0,0}, a1 = {0,0,0,0}, a2 = {0,0,0,0}, a3 = {0,0,0,0};
#pragma unroll
    for (int jj = 0; jj < 32; ++jj) {
      int j = j0 + jj;
      float4 w = W4[(size_t)j * 64];
      float c0 = ctx_s[0][j], c1 = ctx_s[1][j], c2 = ctx_s[2][j], c3 = ctx_s[3][j];
      a0.x += c0*w.x; a0.y += c0*w.y; a0.z += c0*w.z; a0.w += c0*w.w;
      a1.x += c1*w.x; a1.y += c1*w.y; a1.z += c1*w.z; a1.w += c1*w.w;
      a2.x += c2*w.x; a2.y += c2*w.y; a2.z += c2*w.z; a2.w += c2*w.w;
      a3.x += c3*w.x; a3.y += c3*w.y; a3.z += c3*w.z; a3.w += c3*w.w;
    }
    *(float4*)&un_s[((wave * BPB + 0) << 8) + 4 * lane] = a0;
    *(float4*)&un_s[((wave * BPB + 1) << 8) + 4 * lane] = a1;
    *(float4*)&un_s[((wave * BPB + 2) << 8) + 4 * lane] = a2;
    *(float4*)&un_s[((wave * BPB + 3) << 8) + 4 * lane] = a3;
  }
  __syncthreads();
  for (int i = t; i < BPB * E; i += 512) {
    int bi = i >> 8, e = i & 255;
    float v = opb[e] + sc_s[bi][e];
#pragma unroll
    for (int w = 0; w < 8; ++w) v += un_s[((w * BPB + bi) << 8) + e];
    q_s[bi][e] = v;                    // reuse q_s as x
  }
  __syncthreads();

  // ---- LayerNorm: waves 0..3, one batch each ----
  if (wave < BPB) {
    float v0 = q_s[wave][lane], v1 = q_s[wave][lane + 64],
          v2 = q_s[wave][lane + 128], v3 = q_s[wave][lane + 192];
    float s1 = v0 + v1 + v2 + v3;
#pragma unroll
    for (int o = 32; o; o >>= 1) s1 += __shfl_xor(s1, o);
    float mu = s1 * (1.0f / E);
    float d0 = v0 - mu, d1 = v1 - mu, d2 = v2 - mu, d3 = v3 - mu;
    float s2 = d0*d0 + d1*d1 + d2*d2 + d3*d3;
#pragma unroll
    for (int o = 32; o; o >>= 1) s2 += __shfl_xor(s2, o);
    float inv = 1.0f / sqrtf(s2 * (1.0f / E) + 1e-5f);
    size_t base = (size_t)(b0 + wave) * E;
    fusedO[base + lane      ] = d0 * inv * gamma[lane      ] + beta[lane      ];
    fusedO[base + lane +  64] = d1 * inv * gamma[lane +  64] + beta[lane +  64];
    fusedO[base + lane + 128] = d2 * inv * gamma[lane + 128] + beta[lane + 128];
    fusedO[base + lane + 192] = d3 * inv * gamma[lane + 192] + beta[lane + 192];
  }
}

// ---------------------------------------------------------------------------
extern "C" void kernel_launch(void* const* d_in, const int* in_sizes, int n_in,
                              void* d_out, int out_size, void* d_ws, size_t ws_size,
                              hipStream_t stream) {
  const float* scene = (const float*)d_in[0];
  const float* face  = (const float*)d_in[1];
  const float* obj   = (const float*)d_in[2];
  const int*   fb    = (const int*)d_in[3];
  const int*   ob    = (const int*)d_in[4];
  const float* ipw   = (const float*)d_in[5];
  const float* ipb   = (const float*)d_in[6];
  const float* opw   = (const float*)d_in[7];
  const float* opb   = (const float*)d_in[8];
  const float* gam   = (const float*)d_in[9];
  const float* bet   = (const float*)d_in[10];

  float* fused = (float*)d_out;
  float* attnw = fused + (size_t)B * E;

  // ws: starts (16KB) | WT (768KB)
  int* start_f = (int*)d_ws;
  int* start_o = start_f + (B + 1);
  float* WT   = (float*)((char*)d_ws + (16 << 10));
  float* WqT = WT;
  float* WvT = WT + (size_t)E * E;
  float* WoT = WT + (size_t)2 * E * E;

  prep_kernel<<<197, 256, 0, stream>>>(fb, ob, start_f, start_o, ipw, opw, WT);
  fused_kernel<<<B / BPB, 512, 0, stream>>>(scene, face, obj, ipw, ipb,
                                            WqT, WvT, WoT, opb, gam, bet,
                                            start_f, start_o, fused, attnw);
}